// Round 7
// baseline (166.716 us; speedup 1.0000x reference)
//
#include <hip/hip_runtime.h>
#include <math.h>

// Sizes fixed by the problem: B=2, T=512, E=384, H=64, dk=6.
#define SEQ_T   512
#define E_DIM   384
#define H_NUM   64
#define DKQ     6
#define NROWS   1024              // B*T
#define QKV_ELEMS (NROWS*E_DIM)   // 393216 floats per tensor
#define NCHUNK  4                 // attention s-split

// ---------------------------------------------------------------------------
// Quantum layer, analytic form (verified via Bloch algebra + Heisenberg
// push of Z through the CNOT ring):
//   z_i = cos(a_i)cos(b_i)*cos(x_i) - sin(b_i)*sin(x_i)
//   o0 = z1 z2 z3 z4 z5 ; o1 = z0 z1 ; o_k = o_{k-1} * z_k  (k=2..5)
// ---------------------------------------------------------------------------
__device__ __forceinline__ void qmap6(const float* __restrict__ in,
                                      const float* __restrict__ AB,
                                      float* __restrict__ out)
{
    float z[6];
#pragma unroll
    for (int i = 0; i < 6; ++i) {
        float s, c;
        sincosf(in[i], &s, &c);
        z[i] = AB[i] * c - AB[6 + i] * s;
    }
    float z01 = z[0] * z[1];
    float z12 = z[1] * z[2];
    float z34 = z[3] * z[4];
    out[0] = z12 * z34 * z[5];
    out[1] = z01;
    out[2] = z01 * z[2];
    out[3] = out[2] * z[3];
    out[4] = out[3] * z[4];
    out[5] = out[4] * z[5];
}

// ---------------------------------------------------------------------------
// GEMM 32x48 tile, 64 threads (1 wave), 4x6 micro-tile, kk-major LDS.
// Shared by qkv (with scatter epilogue) and out (row-major epilogue).
// LDS reads per kk: 1 b128 (A, 4 rows) + 3 b64 (B, 6 cols) — conflict-free.
// ---------------------------------------------------------------------------
__device__ __forceinline__ void gemm_32x48(const float* __restrict__ A,
                                           const float* __restrict__ W,
                                           int n0, int e0,
                                           float (&xs)[64][36], float (&ws)[64][52],
                                           float (&acc)[4][6])
{
    const int tid = threadIdx.x;      // 0..63
    const int tx = tid & 7;           // col group (6 cols each)
    const int ty = tid >> 3;          // row group (4 rows each)

#pragma unroll
    for (int i = 0; i < 4; ++i)
#pragma unroll
        for (int j = 0; j < 6; ++j) acc[i][j] = 0.f;

    for (int kc = 0; kc < E_DIM; kc += 64) {
        // Stage A tile (32 rows x 64 kk) into xs[kk][row]
#pragma unroll
        for (int w = 0; w < 8; ++w) {
            const int idx = tid + 64 * w;       // 0..511
            const int row = idx & 31;
            const int kf  = idx >> 5;           // 0..15
            const float4 g = *reinterpret_cast<const float4*>(
                A + (size_t)(n0 + row) * E_DIM + kc + kf * 4);
            xs[kf * 4 + 0][row] = g.x;
            xs[kf * 4 + 1][row] = g.y;
            xs[kf * 4 + 2][row] = g.z;
            xs[kf * 4 + 3][row] = g.w;
        }
        // Stage B tile (48 W-rows x 64 kk) into ws[kk][col]
#pragma unroll
        for (int w = 0; w < 12; ++w) {
            const int idx = tid + 64 * w;       // 0..767
            const int c  = idx % 48;
            const int kf = idx / 48;            // 0..15
            const float4 g = *reinterpret_cast<const float4*>(
                W + (size_t)(e0 + c) * E_DIM + kc + kf * 4);
            ws[kf * 4 + 0][c] = g.x;
            ws[kf * 4 + 1][c] = g.y;
            ws[kf * 4 + 2][c] = g.z;
            ws[kf * 4 + 3][c] = g.w;
        }
        __syncthreads();

#pragma unroll 8
        for (int kk = 0; kk < 64; ++kk) {
            const float4 a = *reinterpret_cast<const float4*>(&xs[kk][ty * 4]);
            const float2 b0 = *reinterpret_cast<const float2*>(&ws[kk][tx * 6 + 0]);
            const float2 b1 = *reinterpret_cast<const float2*>(&ws[kk][tx * 6 + 2]);
            const float2 b2 = *reinterpret_cast<const float2*>(&ws[kk][tx * 6 + 4]);
            const float av[4] = {a.x, a.y, a.z, a.w};
            const float bv[6] = {b0.x, b0.y, b1.x, b1.y, b2.x, b2.y};
#pragma unroll
            for (int i = 0; i < 4; ++i)
#pragma unroll
                for (int j = 0; j < 6; ++j) acc[i][j] += av[i] * bv[j];
        }
        __syncthreads();
    }
}

// ---------------------------------------------------------------------------
// Kernel A: Y = x @ [Wq;Wk;Wv]^T + bias, scattered to (B,H,T,6) buffers.
// grid (32, 24): by 0..7 -> Q, 8..15 -> K, 16..23 -> V. block 64.
// ---------------------------------------------------------------------------
__global__ __launch_bounds__(64)
void qkv_gemm(const float* __restrict__ x,
              const float* __restrict__ Wq, const float* __restrict__ bq,
              const float* __restrict__ Wk, const float* __restrict__ bk,
              const float* __restrict__ Wv, const float* __restrict__ bv,
              float* __restrict__ qb, float* __restrict__ kb, float* __restrict__ vb)
{
    __shared__ __align__(16) float xs[64][36];
    __shared__ __align__(16) float ws[64][52];

    const int n0 = blockIdx.x * 32;
    const int by = blockIdx.y;
    const int sel = by >> 3;                  // 0=Q,1=K,2=V
    const int e0 = (by & 7) * 48;

    const float* W; const float* bias; float* ob;
    if (sel == 0)      { W = Wq; bias = bq; ob = qb; }
    else if (sel == 1) { W = Wk; bias = bk; ob = kb; }
    else               { W = Wv; bias = bv; ob = vb; }

    float acc[4][6];
    gemm_32x48(x, W, n0, e0, xs, ws, acc);

    const int tx = threadIdx.x & 7;
    const int ty = threadIdx.x >> 3;
    const int h = (e0 / 6) + tx;              // head (whole 6-wide slice per thread)
    const float2 bi0 = *reinterpret_cast<const float2*>(bias + e0 + tx * 6 + 0);
    const float2 bi1 = *reinterpret_cast<const float2*>(bias + e0 + tx * 6 + 2);
    const float2 bi2 = *reinterpret_cast<const float2*>(bias + e0 + tx * 6 + 4);

#pragma unroll
    for (int i = 0; i < 4; ++i) {
        const int n = n0 + ty * 4 + i;        // b*512 + t
        const int b = n >> 9;
        const int t = n & 511;
        float* rp = ob + (((size_t)(b * H_NUM + h) * SEQ_T) + t) * DKQ;
        float2 w0 = {acc[i][0] + bi0.x, acc[i][1] + bi0.y};
        float2 w1 = {acc[i][2] + bi1.x, acc[i][3] + bi1.y};
        float2 w2 = {acc[i][4] + bi2.x, acc[i][5] + bi2.y};
        *reinterpret_cast<float2*>(rp + 0) = w0;
        *reinterpret_cast<float2*>(rp + 2) = w1;
        *reinterpret_cast<float2*>(rp + 4) = w2;
    }
}

// ---------------------------------------------------------------------------
// Kernel B: in-place quantum map of qb,kb,vb (contiguous). One thread maps
// two 6-float rows (48B = 3 aligned float4). grid 384 x 256 covers
// 98304 pairs = 3 * 65536 rows exactly.
// ---------------------------------------------------------------------------
__global__ __launch_bounds__(256)
void qmap_inplace(float* __restrict__ qb, const float* __restrict__ qparams)
{
    const int pid = blockIdx.x * 256 + threadIdx.x;   // 0..98303
    float AB[12];
#pragma unroll
    for (int i = 0; i < 6; ++i) {
        const float a = qparams[i * 2 + 0];
        const float b = qparams[i * 2 + 1];
        AB[i]     = cosf(a) * cosf(b);
        AB[6 + i] = sinf(b);
    }
    float4* p = reinterpret_cast<float4*>(qb + (size_t)pid * 12);
    float4 g0 = p[0], g1 = p[1], g2 = p[2];
    float in0[6] = {g0.x, g0.y, g0.z, g0.w, g1.x, g1.y};
    float in1[6] = {g1.z, g1.w, g2.x, g2.y, g2.z, g2.w};
    float o0[6], o1[6];
    qmap6(in0, AB, o0);
    qmap6(in1, AB, o1);
    p[0] = make_float4(o0[0], o0[1], o0[2], o0[3]);
    p[1] = make_float4(o0[4], o0[5], o1[0], o1[1]);
    p[2] = make_float4(o1[2], o1[3], o1[4], o1[5]);
}

// ---------------------------------------------------------------------------
// Kernel C: attention partial sums. grid (128 bh, 4 s-chunks), block 128
// (2 waves). Each thread: 4 q-rows (t, t+128, t+256, t+384) over a 128-row
// s-chunk staged in LDS. No max subtraction (|score| <= sqrt(6)) -> partial
// (accv, denom) are plain associative sums.
// part layout: [chunk][q][bh][8]  (scattered writes, coalesced reduce reads)
// ---------------------------------------------------------------------------
__global__ __launch_bounds__(128)
void attn_partial(const float* __restrict__ qb,
                  const float* __restrict__ kb,
                  const float* __restrict__ vb,
                  float* __restrict__ part)
{
    __shared__ __align__(16) float kv[128][12];   // 6 KB

    const int bh = blockIdx.x;        // b*64 + h
    const int c  = blockIdx.y;        // s-chunk
    const int t  = threadIdx.x;       // 0..127

    // Stage K/V row s = c*128 + t (pre-mapped)
    {
        const float* kr = kb + ((size_t)bh * SEQ_T + c * 128 + t) * DKQ;
        const float* vr = vb + ((size_t)bh * SEQ_T + c * 128 + t) * DKQ;
        const float2 k0 = *reinterpret_cast<const float2*>(kr + 0);
        const float2 k1 = *reinterpret_cast<const float2*>(kr + 2);
        const float2 k2 = *reinterpret_cast<const float2*>(kr + 4);
        const float2 v0 = *reinterpret_cast<const float2*>(vr + 0);
        const float2 v1 = *reinterpret_cast<const float2*>(vr + 2);
        const float2 v2 = *reinterpret_cast<const float2*>(vr + 4);
        float4* kvp = reinterpret_cast<float4*>(&kv[t][0]);
        kvp[0] = make_float4(k0.x, k0.y, k1.x, k1.y);
        kvp[1] = make_float4(k2.x, k2.y, v0.x, v0.y);
        kvp[2] = make_float4(v1.x, v1.y, v2.x, v2.y);
    }

    // Load 4 q-rows (pre-mapped), pre-scaled by 1/sqrt(6)
    const float inv_sqrt_dk = 0.40824829046386296f;
    float qrow[4][6];
#pragma unroll
    for (int r = 0; r < 4; ++r) {
        const float* qp = qb + ((size_t)bh * SEQ_T + r * 128 + t) * DKQ;
        const float2 q0 = *reinterpret_cast<const float2*>(qp + 0);
        const float2 q1 = *reinterpret_cast<const float2*>(qp + 2);
        const float2 q2 = *reinterpret_cast<const float2*>(qp + 4);
        qrow[r][0] = q0.x * inv_sqrt_dk; qrow[r][1] = q0.y * inv_sqrt_dk;
        qrow[r][2] = q1.x * inv_sqrt_dk; qrow[r][3] = q1.y * inv_sqrt_dk;
        qrow[r][4] = q2.x * inv_sqrt_dk; qrow[r][5] = q2.y * inv_sqrt_dk;
    }
    __syncthreads();

    float accv[4][6];
    float den[4] = {0.f, 0.f, 0.f, 0.f};
#pragma unroll
    for (int r = 0; r < 4; ++r)
#pragma unroll
        for (int d = 0; d < 6; ++d) accv[r][d] = 0.f;

    const float4* kv4 = reinterpret_cast<const float4*>(&kv[0][0]);
#pragma unroll 2
    for (int s = 0; s < 128; ++s) {
        const float4 r0 = kv4[3 * s + 0];   // k0..k3
        const float4 r1 = kv4[3 * s + 1];   // k4,k5,v0,v1
        const float4 r2 = kv4[3 * s + 2];   // v2..v5
#pragma unroll
        for (int r = 0; r < 4; ++r) {
            const float sc = qrow[r][0] * r0.x + qrow[r][1] * r0.y + qrow[r][2] * r0.z
                           + qrow[r][3] * r0.w + qrow[r][4] * r1.x + qrow[r][5] * r1.y;
            const float e = __expf(sc);
            den[r] += e;
            accv[r][0] += e * r1.z; accv[r][1] += e * r1.w;
            accv[r][2] += e * r2.x; accv[r][3] += e * r2.y;
            accv[r][4] += e * r2.z; accv[r][5] += e * r2.w;
        }
    }

#pragma unroll
    for (int r = 0; r < 4; ++r) {
        const int q = r * 128 + t;
        float4* pp = reinterpret_cast<float4*>(
            part + ((size_t)((c * SEQ_T + q) * 128 + bh)) * 8);
        pp[0] = make_float4(accv[r][0], accv[r][1], accv[r][2], accv[r][3]);
        pp[1] = make_float4(accv[r][4], accv[r][5], den[r], 0.f);
    }
}

// ---------------------------------------------------------------------------
// Kernel D: reduce partials -> merged (B,T,E). grid 256 x 256; one thread per
// (q, bh), bh fastest for coalesced partial reads.
// ---------------------------------------------------------------------------
__global__ __launch_bounds__(256)
void attn_reduce(const float* __restrict__ part, float* __restrict__ merged)
{
    const int idx = blockIdx.x * 256 + threadIdx.x;   // 0..65535
    const int bh = idx & 127;
    const int q  = idx >> 7;

    float acc[6] = {0.f, 0.f, 0.f, 0.f, 0.f, 0.f};
    float den = 0.f;
#pragma unroll
    for (int c = 0; c < NCHUNK; ++c) {
        const float4* pp = reinterpret_cast<const float4*>(
            part + ((size_t)((c * SEQ_T + q) * 128 + bh)) * 8);
        const float4 a = pp[0];
        const float4 b = pp[1];
        acc[0] += a.x; acc[1] += a.y; acc[2] += a.z; acc[3] += a.w;
        acc[4] += b.x; acc[5] += b.y; den += b.z;
    }
    const float r = 1.0f / den;
    const int b = bh >> 6;
    const int h = bh & 63;
    float* mp = merged + ((size_t)(b * SEQ_T + q)) * E_DIM + h * DKQ;
    float2 w0 = {acc[0] * r, acc[1] * r};
    float2 w1 = {acc[2] * r, acc[3] * r};
    float2 w2 = {acc[4] * r, acc[5] * r};
    *reinterpret_cast<float2*>(mp + 0) = w0;
    *reinterpret_cast<float2*>(mp + 2) = w1;
    *reinterpret_cast<float2*>(mp + 4) = w2;
}

// ---------------------------------------------------------------------------
// Kernel E: out = merged @ Wo^T + bo. grid (32, 8) = 256 blocks, block 64.
// ---------------------------------------------------------------------------
__global__ __launch_bounds__(64)
void out_gemm(const float* __restrict__ merged,
              const float* __restrict__ Wo, const float* __restrict__ bo,
              float* __restrict__ out)
{
    __shared__ __align__(16) float xs[64][36];
    __shared__ __align__(16) float ws[64][52];

    const int n0 = blockIdx.x * 32;
    const int e0 = blockIdx.y * 48;

    float acc[4][6];
    gemm_32x48(merged, Wo, n0, e0, xs, ws, acc);

    const int tx = threadIdx.x & 7;
    const int ty = threadIdx.x >> 3;
    const float2 bi0 = *reinterpret_cast<const float2*>(bo + e0 + tx * 6 + 0);
    const float2 bi1 = *reinterpret_cast<const float2*>(bo + e0 + tx * 6 + 2);
    const float2 bi2 = *reinterpret_cast<const float2*>(bo + e0 + tx * 6 + 4);

#pragma unroll
    for (int i = 0; i < 4; ++i) {
        const int n = n0 + ty * 4 + i;
        float* rp = out + (size_t)n * E_DIM + e0 + tx * 6;
        float2 w0 = {acc[i][0] + bi0.x, acc[i][1] + bi0.y};
        float2 w1 = {acc[i][2] + bi1.x, acc[i][3] + bi1.y};
        float2 w2 = {acc[i][4] + bi2.x, acc[i][5] + bi2.y};
        *reinterpret_cast<float2*>(rp + 0) = w0;
        *reinterpret_cast<float2*>(rp + 2) = w1;
        *reinterpret_cast<float2*>(rp + 4) = w2;
    }
}

// ---------------------------------------------------------------------------
extern "C" void kernel_launch(void* const* d_in, const int* in_sizes, int n_in,
                              void* d_out, int out_size, void* d_ws, size_t ws_size,
                              hipStream_t stream)
{
    const float* x  = (const float*)d_in[0];
    const float* Wq = (const float*)d_in[1];
    const float* bq = (const float*)d_in[2];
    const float* Wk = (const float*)d_in[3];
    const float* bk = (const float*)d_in[4];
    const float* Wv = (const float*)d_in[5];
    const float* bv = (const float*)d_in[6];
    const float* Wo = (const float*)d_in[7];
    const float* bo = (const float*)d_in[8];
    const float* qp = (const float*)d_in[9];
    float* out = (float*)d_out;

    float* qb     = (float*)d_ws;                 // qb,kb,vb contiguous (qmap relies on it)
    float* kb     = qb + QKV_ELEMS;
    float* vb     = kb + QKV_ELEMS;
    float* merged = vb + QKV_ELEMS;
    float* part   = merged + QKV_ELEMS;           // 4*512*128*8 floats = 8 MB
    // total ws: ~14.1 MB

    qkv_gemm<<<dim3(32, 24), 64, 0, stream>>>(x, Wq, bq, Wk, bk, Wv, bv, qb, kb, vb);
    qmap_inplace<<<384, 256, 0, stream>>>(qb, qp);
    attn_partial<<<dim3(128, NCHUNK), 128, 0, stream>>>(qb, kb, vb, part);
    attn_reduce<<<256, 256, 0, stream>>>(part, merged);
    out_gemm<<<dim3(32, 8), 64, 0, stream>>>(merged, Wo, bo, out);
}